// Round 3
// baseline (6560.967 us; speedup 1.0000x reference)
//
#include <hip/hip_runtime.h>
#include <cmath>

#define N_LAYERS 24
#define D_MODEL 768
#define D_INNER 1536
#define D_STATE 16
#define DT_RANK 48
#define CONV_K 4
#define VOCAB 50280
#define SEQ 8
#define BATCH 64
#define NTOK (BATCH*SEQ)     /* 512 */
#define EPS 1e-5f
#define XZ_LD (2*D_INNER)    /* 3072 */

typedef __attribute__((ext_vector_type(8))) __bf16 bf16x8;
typedef __attribute__((ext_vector_type(4))) float f32x4;

#define LDSW 40   /* bf16 elems per LDS row: 32 data + 8 pad -> 80B rows, bank-uniform */

__device__ inline void stage8(__bf16* dst, const float* src) {
    float4 a0 = *(const float4*)src;
    float4 a1 = *(const float4*)(src + 4);
    bf16x8 v;
    v[0] = (__bf16)a0.x; v[1] = (__bf16)a0.y; v[2] = (__bf16)a0.z; v[3] = (__bf16)a0.w;
    v[4] = (__bf16)a1.x; v[5] = (__bf16)a1.y; v[6] = (__bf16)a1.z; v[7] = (__bf16)a1.w;
    *(bf16x8*)dst = v;
}

// ---------------- embedding gather ----------------
__global__ void embed_gather(const int* __restrict__ ids, const float* __restrict__ embed,
                             float* __restrict__ h) {
    int row = blockIdx.x;
    int b = row / SEQ, t = row % SEQ;
    int id = ids[b * 64 + t];
    const float4* src = (const float4*)(embed + (size_t)id * D_MODEL);
    float4* dst = (float4*)(h + (size_t)row * D_MODEL);
    dst[threadIdx.x] = src[threadIdx.x];  // 192 threads * 4 = 768
}

// ---------------- rmsnorm ----------------
__global__ void rmsnorm_k(const float* __restrict__ x, const float* __restrict__ w,
                          float* __restrict__ out, int D) {
    int row = blockIdx.x;
    const float* xr = x + (size_t)row * D;
    float s = 0.f;
    for (int i = threadIdx.x; i < D; i += blockDim.x) { float v = xr[i]; s += v * v; }
    #pragma unroll
    for (int off = 32; off; off >>= 1) s += __shfl_down(s, off);
    __shared__ float red[8];
    int lane = threadIdx.x & 63, wid = threadIdx.x >> 6;
    if (lane == 0) red[wid] = s;
    __syncthreads();
    if (threadIdx.x == 0) {
        float tot = 0.f;
        for (int i = 0; i < (int)(blockDim.x >> 6); i++) tot += red[i];
        red[0] = rsqrtf(tot / (float)D + EPS);
    }
    __syncthreads();
    float r = red[0];
    for (int i = threadIdx.x; i < D; i += blockDim.x)
        out[(size_t)row * D + i] = xr[i] * r * w[i];
}

// ---------------- mgemm_big: C[M,N] = A[M,K] @ B[N,K]^T, BM=64 BN=256 BK=32 ----------------
// 4 waves; wave w computes 64 rows x 64 cols (cols w*64..w*64+63): 16 MFMA/iter.
// Requires N % 256 == 0, K-chunk % 32 == 0, M % 64 == 0. epi: 0 = store, 3 = atomicAdd.
__global__ __launch_bounds__(256) void mgemm_big(
    const float* __restrict__ A, int lda,
    const float* __restrict__ B, int ldb,
    float* __restrict__ C, int ldc,
    int N, int K, int KC, int epi)
{
    __shared__ __align__(16) __bf16 As[64 * LDSW];    // 5 KB
    __shared__ __align__(16) __bf16 Bs[256 * LDSW];   // 20 KB
    int tid = threadIdx.x;
    int n0 = blockIdx.x * 256, m0 = blockIdx.y * 64;
    int kstart = blockIdx.z * KC;
    int kend = kstart + KC; if (kend > K) kend = K;
    int wave = tid >> 6, lane = tid & 63;
    int l15 = lane & 15, quad = lane >> 4;
    int srow = tid >> 2;           // 0..63
    int skq = (tid & 3) * 8;       // k-chunk offset (floats)

    f32x4 acc[4][4];
    #pragma unroll
    for (int i = 0; i < 4; i++)
        #pragma unroll
        for (int j = 0; j < 4; j++) acc[i][j] = (f32x4){0.f, 0.f, 0.f, 0.f};

    for (int k0 = kstart; k0 < kend; k0 += 32) {
        // stage A: rows 0..63 (r=0), B: rows 0..255 (r=1..4)
        stage8(&As[srow * LDSW + skq], A + (size_t)(m0 + srow) * lda + k0 + skq);
        #pragma unroll
        for (int r = 1; r < 5; r++) {
            int brow = (r - 1) * 64 + srow;
            stage8(&Bs[brow * LDSW + skq], B + (size_t)(n0 + brow) * ldb + k0 + skq);
        }
        __syncthreads();
        bf16x8 af[4];
        #pragma unroll
        for (int jm = 0; jm < 4; jm++)
            af[jm] = *(bf16x8*)&As[(jm * 16 + l15) * LDSW + quad * 8];
        #pragma unroll
        for (int jn = 0; jn < 4; jn++) {
            bf16x8 bf = *(bf16x8*)&Bs[(wave * 64 + jn * 16 + l15) * LDSW + quad * 8];
            #pragma unroll
            for (int jm = 0; jm < 4; jm++)
                acc[jm][jn] = __builtin_amdgcn_mfma_f32_16x16x32_bf16(af[jm], bf, acc[jm][jn], 0, 0, 0);
        }
        __syncthreads();
    }
    // epilogue: col = lane&15, row = quad*4 + reg
    #pragma unroll
    for (int jm = 0; jm < 4; jm++) {
        #pragma unroll
        for (int jn = 0; jn < 4; jn++) {
            int n = n0 + wave * 64 + jn * 16 + l15;
            #pragma unroll
            for (int r = 0; r < 4; r++) {
                int m = m0 + jm * 16 + quad * 4 + r;
                size_t ci = (size_t)m * ldc + n;
                if (epi == 3) atomicAdd(&C[ci], acc[jm][jn][r]);
                else C[ci] = acc[jm][jn][r];
            }
        }
    }
}

// ---------------- mgemm_tall: C[512,N] = A[512,K] @ B[N,K]^T, BM=512 BN=64 BK=32 ----------------
// For logits: each block covers ALL tokens -> B (embed) fetched exactly once.
// wave w computes rows w*128..w*128+127 x 64 cols: 32 MFMA/iter.
__global__ __launch_bounds__(256) void mgemm_tall(
    const float* __restrict__ A, int lda,
    const float* __restrict__ B, int ldb,
    float* __restrict__ C, int ldc,
    int N, int K)
{
    __shared__ __align__(16) __bf16 As[512 * LDSW];  // 40 KB
    __shared__ __align__(16) __bf16 Bs[64 * LDSW];   // 5 KB
    int tid = threadIdx.x;
    int n0 = blockIdx.x * 64;
    int wave = tid >> 6, lane = tid & 63;
    int l15 = lane & 15, quad = lane >> 4;
    int srow = tid >> 2;
    int skq = (tid & 3) * 8;

    f32x4 acc[8][4];
    #pragma unroll
    for (int i = 0; i < 8; i++)
        #pragma unroll
        for (int j = 0; j < 4; j++) acc[i][j] = (f32x4){0.f, 0.f, 0.f, 0.f};

    int brow = n0 + srow;
    bool bvalid = brow < N;

    for (int k0 = 0; k0 < K; k0 += 32) {
        // stage A: 512 rows, 8 chunks/thread
        #pragma unroll
        for (int r = 0; r < 8; r++) {
            int arow = r * 64 + srow;
            stage8(&As[arow * LDSW + skq], A + (size_t)arow * lda + k0 + skq);
        }
        // stage B: 64 rows, 1 chunk/thread (guarded)
        if (bvalid) {
            stage8(&Bs[srow * LDSW + skq], B + (size_t)brow * ldb + k0 + skq);
        } else {
            bf16x8 z = {};
            *(bf16x8*)&Bs[srow * LDSW + skq] = z;
        }
        __syncthreads();
        bf16x8 bfr[4];
        #pragma unroll
        for (int jn = 0; jn < 4; jn++)
            bfr[jn] = *(bf16x8*)&Bs[(jn * 16 + l15) * LDSW + quad * 8];
        #pragma unroll
        for (int jm = 0; jm < 8; jm++) {
            bf16x8 af = *(bf16x8*)&As[(wave * 128 + jm * 16 + l15) * LDSW + quad * 8];
            #pragma unroll
            for (int jn = 0; jn < 4; jn++)
                acc[jm][jn] = __builtin_amdgcn_mfma_f32_16x16x32_bf16(af, bfr[jn], acc[jm][jn], 0, 0, 0);
        }
        __syncthreads();
    }
    #pragma unroll
    for (int jm = 0; jm < 8; jm++) {
        #pragma unroll
        for (int jn = 0; jn < 4; jn++) {
            int n = n0 + jn * 16 + l15;
            if (n < N) {
                #pragma unroll
                for (int r = 0; r < 4; r++) {
                    int m = wave * 128 + jm * 16 + quad * 4 + r;
                    C[(size_t)m * ldc + n] = acc[jm][jn][r];
                }
            }
        }
    }
}

// ---------------- fused SSM: conv+silu -> x_proj -> dt_proj+softplus -> scan -> z-gate ----------------
// One block per batch element. xc (conv output) and proj live in LDS; everything fp32.
#define XC_LD 1544  /* 1536 + 8 pad; keeps float4 alignment, offsets banks per row */
__global__ __launch_bounds__(256) void ssm_fused(
    const float* __restrict__ xz, const int* __restrict__ mask,
    const float* __restrict__ cw, const float* __restrict__ cb,
    const float* __restrict__ xpw, const float* __restrict__ dtw,
    const float* __restrict__ dtb, const float* __restrict__ A_log,
    const float* __restrict__ Dp, float* __restrict__ y)
{
    __shared__ float xc[SEQ * XC_LD];       // ~49.4 KB
    __shared__ float pr[SEQ * 80];          // 2.5 KB
    __shared__ float mf[SEQ];
    int b = blockIdx.x, tid = threadIdx.x;
    if (tid < SEQ) mf[tid] = (float)mask[b * 64 + tid];
    __syncthreads();

    // ---- conv + bias + silu + mask ----
    for (int d = tid; d < D_INNER; d += 256) {
        float4 c = *(const float4*)(cw + d * CONV_K);
        float bias = cb[d];
        float xm[SEQ];
        #pragma unroll
        for (int t = 0; t < SEQ; t++)
            xm[t] = xz[(size_t)(b * SEQ + t) * XZ_LD + d] * mf[t];
        #pragma unroll
        for (int t = 0; t < SEQ; t++) {
            float acc = bias + c.w * xm[t];
            if (t >= 1) acc += c.z * xm[t - 1];
            if (t >= 2) acc += c.y * xm[t - 2];
            if (t >= 3) acc += c.x * xm[t - 3];
            float s = acc / (1.f + expf(-acc));
            xc[t * XC_LD + d] = s * mf[t];
        }
    }
    __syncthreads();

    // ---- x_proj: pr[t][e] = xc[t,:] . xpw[e,:]  (640 outputs, K=1536) ----
    for (int idx = tid; idx < SEQ * 80; idx += 256) {
        int t = idx / 80, e = idx % 80;
        const float4* wrow = (const float4*)(xpw + (size_t)e * D_INNER);
        const float* xr = &xc[t * XC_LD];
        float s = 0.f;
        #pragma unroll 8
        for (int k4 = 0; k4 < D_INNER / 4; k4++) {
            float4 w = wrow[k4];
            s += w.x * xr[k4 * 4] + w.y * xr[k4 * 4 + 1]
               + w.z * xr[k4 * 4 + 2] + w.w * xr[k4 * 4 + 3];
        }
        pr[t * 80 + e] = s;
    }
    __syncthreads();

    // ---- dt (recomputed per lane) + selective scan + D-skip + z-gate ----
    for (int d = tid; d < D_INNER; d += 256) {
        float wr[DT_RANK];
        const float4* dtr = (const float4*)(dtw + (size_t)d * DT_RANK);
        #pragma unroll
        for (int q = 0; q < DT_RANK / 4; q++) {
            float4 v = dtr[q];
            wr[q * 4] = v.x; wr[q * 4 + 1] = v.y; wr[q * 4 + 2] = v.z; wr[q * 4 + 3] = v.w;
        }
        float dtbv = dtb[d];
        float Av[D_STATE];
        #pragma unroll
        for (int q = 0; q < D_STATE / 4; q++) {
            float4 v = *(const float4*)(A_log + (size_t)d * D_STATE + q * 4);
            Av[q * 4] = -expf(v.x); Av[q * 4 + 1] = -expf(v.y);
            Av[q * 4 + 2] = -expf(v.z); Av[q * 4 + 3] = -expf(v.w);
        }
        float Dv = Dp[d];
        float h[D_STATE];
        #pragma unroll
        for (int n = 0; n < D_STATE; n++) h[n] = 0.f;
        for (int t = 0; t < SEQ; t++) {
            float s = dtbv;
            #pragma unroll
            for (int r = 0; r < DT_RANK; r++) s += pr[t * 80 + r] * wr[r];
            float dtv = (s > 20.f) ? s : log1pf(expf(s));
            float xv = xc[t * XC_LD + d];
            float yv = 0.f;
            #pragma unroll
            for (int n = 0; n < D_STATE; n++) {
                h[n] = expf(dtv * Av[n]) * h[n] + dtv * pr[t * 80 + DT_RANK + n] * xv;
                yv += h[n] * pr[t * 80 + DT_RANK + D_STATE + n];
            }
            yv += xv * Dv;
            float z = xz[(size_t)(b * SEQ + t) * XZ_LD + D_INNER + d];
            yv *= z / (1.f + expf(-z));
            y[(size_t)(b * SEQ + t) * D_INNER + d] = yv;
        }
    }
}

extern "C" void kernel_launch(void* const* d_in, const int* in_sizes, int n_in,
                              void* d_out, int out_size, void* d_ws, size_t ws_size,
                              hipStream_t stream) {
    const int*   full_ids = (const int*)  d_in[0];
    const int*   full_mask= (const int*)  d_in[1];
    const float* embed    = (const float*)d_in[3];
    const float* norm_w   = (const float*)d_in[4];
    const float* in_w     = (const float*)d_in[5];
    const float* conv_w   = (const float*)d_in[6];
    const float* conv_b   = (const float*)d_in[7];
    const float* xp_w     = (const float*)d_in[8];
    const float* dtp_w    = (const float*)d_in[9];
    const float* dtp_b    = (const float*)d_in[10];
    const float* A_log    = (const float*)d_in[11];
    const float* Dp       = (const float*)d_in[12];
    const float* out_w    = (const float*)d_in[13];
    const float* norm_f_w = (const float*)d_in[14];
    float* out = (float*)d_out;

    char* ws = (char*)d_ws;
    size_t off = 0;
    auto alloc = [&](size_t nfloats) {
        float* p = (float*)(ws + off);
        off += ((nfloats * 4 + 255) / 256) * 256;
        return p;
    };
    float* h  = alloc((size_t)NTOK * D_MODEL);
    float* hn = alloc((size_t)NTOK * D_MODEL);
    float* xz = alloc((size_t)NTOK * XZ_LD);
    float* y  = alloc((size_t)NTOK * D_INNER);

    embed_gather<<<NTOK, 192, 0, stream>>>(full_ids, embed, h);

    for (int l = 0; l < N_LAYERS; l++) {
        const float* inw  = in_w  + (size_t)l * 2 * D_INNER * D_MODEL;
        const float* cw   = conv_w + (size_t)l * D_INNER * CONV_K;
        const float* cb   = conv_b + (size_t)l * D_INNER;
        const float* xpw  = xp_w  + (size_t)l * (DT_RANK + 2 * D_STATE) * D_INNER;
        const float* dtw  = dtp_w + (size_t)l * D_INNER * DT_RANK;
        const float* dtb  = dtp_b + (size_t)l * D_INNER;
        const float* Al   = A_log + (size_t)l * D_INNER * D_STATE;
        const float* Dl   = Dp    + (size_t)l * D_INNER;
        const float* ow   = out_w + (size_t)l * D_MODEL * D_INNER;

        rmsnorm_k<<<NTOK, 256, 0, stream>>>(h, norm_w + (size_t)l * D_MODEL, hn, D_MODEL);
        // xz = hn @ in_w^T  (512 x 3072, K=768): grid (12, 8)
        mgemm_big<<<dim3(2 * D_INNER / 256, NTOK / 64, 1), 256, 0, stream>>>(
            hn, D_MODEL, inw, D_MODEL, xz, XZ_LD, 2 * D_INNER, D_MODEL, D_MODEL, 0);
        // fused conv/x_proj/dt/scan/gate -> y
        ssm_fused<<<BATCH, 256, 0, stream>>>(xz, full_mask, cw, cb, xpw, dtw, dtb, Al, Dl, y);
        // h += y @ out_w^T  (512 x 768, K=1536): split-K 4, atomic into residual
        mgemm_big<<<dim3(D_MODEL / 256, NTOK / 64, 4), 256, 0, stream>>>(
            y, D_INNER, ow, D_INNER, h, D_MODEL, D_MODEL, D_INNER, 384, 3);
    }

    rmsnorm_k<<<NTOK, 256, 0, stream>>>(h, norm_f_w, hn, D_MODEL);
    // logits = hn @ embed^T  (512 x 50280, K=768): tall tile, embed fetched once
    mgemm_tall<<<dim3((VOCAB + 63) / 64), 256, 0, stream>>>(
        hn, D_MODEL, embed, D_MODEL, out, VOCAB, VOCAB, D_MODEL);
}